// Round 1
// baseline (9319.463 us; speedup 1.0000x reference)
//
#include <hip/hip_runtime.h>
#include <math.h>

#define THREADS 256

__global__ void deg_kernel(const int* __restrict__ pdst, const int* __restrict__ ndst,
                           float* degp, float* degn, int E) {
    int e = blockIdx.x * blockDim.x + threadIdx.x;
    if (e < E) {
        atomicAdd(&degp[pdst[e]], 1.0f);
        atomicAdd(&degn[ndst[e]], 1.0f);
    }
}

__global__ void inv_kernel(float* deg, int n) {
    int i = blockIdx.x * blockDim.x + threadIdx.x;
    if (i < n) deg[i] = 1.0f / fmaxf(deg[i], 1.0f);
}

// one edge handled by 32 threads, each moving a float4 chunk of the 128-wide row
__global__ void scatter_add_kernel(const float* __restrict__ feat,
                                   const int* __restrict__ src,
                                   const int* __restrict__ dst,
                                   float* out, int ostride, int coff, int E) {
    long idx = (long)blockIdx.x * blockDim.x + threadIdx.x;
    if (idx >= (long)E * 32) return;
    int e = (int)(idx >> 5);
    int c = ((int)idx & 31) * 4;
    int s = src[e], d = dst[e];
    float4 v = *(const float4*)(feat + (long)s * 128 + c);
    float* o = out + (long)d * ostride + coff + c;
    atomicAdd(o + 0, v.x);
    atomicAdd(o + 1, v.y);
    atomicAdd(o + 2, v.z);
    atomicAdd(o + 3, v.w);
}

// GEMM with tanh epilogue. Input row k-range assembled from up to 3 concatenated
// parts, each optionally scaled per-row (folds the seg-mean divide in).
// In-place safe: each block stages its own 32 rows x K into LDS before storing.
template<int K, int OUTC>
__global__ __launch_bounds__(256) void gemm_tanh(
    const float* p0, const float* s0, int st0, int w0,
    const float* p1, const float* s1, int st1, int w1,
    const float* p2, int st2,
    const float* __restrict__ W, const float* __restrict__ bias,
    float* out, int ostride, int n)
{
    __shared__ float Alds[32][K];
    int tid = threadIdx.x;
    int rowBase = blockIdx.x * 32;

    for (int idx = tid; idx < 32 * K; idx += 256) {
        int r = idx / K;
        int k = idx - r * K;
        int row = rowBase + r;
        float v = 0.0f;
        if (row < n) {
            if (k < w0) {
                v = p0[(long)row * st0 + k] * (s0 ? s0[row] : 1.0f);
            } else if (k < w0 + w1) {
                v = p1[(long)row * st1 + (k - w0)] * (s1 ? s1[row] : 1.0f);
            } else {
                v = p2[(long)row * st2 + (k - w0 - w1)];
            }
        }
        Alds[r][k] = v;
    }
    __syncthreads();

    constexpr int RPT = 32 * OUTC / 256;   // outputs per thread
    constexpr int RSTEP = 256 / OUTC;      // row stride between a thread's outputs
    int col = tid % OUTC;
    int r0 = tid / OUTC;

    float acc[RPT];
    float bv = bias[col];
#pragma unroll
    for (int i = 0; i < RPT; i++) acc[i] = bv;

    for (int k = 0; k < K; k += 4) {
        float w0v = W[(long)(k + 0) * OUTC + col];
        float w1v = W[(long)(k + 1) * OUTC + col];
        float w2v = W[(long)(k + 2) * OUTC + col];
        float w3v = W[(long)(k + 3) * OUTC + col];
#pragma unroll
        for (int i = 0; i < RPT; i++) {
            float4 a = *(const float4*)&Alds[r0 + i * RSTEP][k];
            acc[i] = fmaf(a.x, w0v, acc[i]);
            acc[i] = fmaf(a.y, w1v, acc[i]);
            acc[i] = fmaf(a.z, w2v, acc[i]);
            acc[i] = fmaf(a.w, w3v, acc[i]);
        }
    }

#pragma unroll
    for (int i = 0; i < RPT; i++) {
        int row = rowBase + r0 + i * RSTEP;
        if (row < n) out[(long)row * ostride + col] = tanhf(acc[i]);
    }
}

extern "C" void kernel_launch(void* const* d_in, const int* in_sizes, int n_in,
                              void* d_out, int out_size, void* d_ws, size_t ws_size,
                              hipStream_t stream) {
    const float* x       = (const float*)d_in[0];
    const int*   pos_src = (const int*)d_in[1];
    const int*   pos_dst = (const int*)d_in[2];
    const int*   neg_src = (const int*)d_in[3];
    const int*   neg_dst = (const int*)d_in[4];
    const float* W_oneB  = (const float*)d_in[5];
    const float* b_oneB  = (const float*)d_in[6];
    const float* W_oneH  = (const float*)d_in[7];
    const float* b_oneH  = (const float*)d_in[8];
    const float* W_twoB  = (const float*)d_in[9];
    const float* b_twoB  = (const float*)d_in[10];
    const float* W_twoH  = (const float*)d_in[11];
    const float* b_twoH  = (const float*)d_in[12];
    const float* W_four  = (const float*)d_in[13];
    const float* b_four  = (const float*)d_in[14];

    const int D = in_sizes[6];        // 128
    const int N = in_sizes[0] / D;    // 50000
    const int E = in_sizes[1];        // 800000

    float* ws = (float*)d_ws;
    size_t ND = (size_t)N * D;
    // layout: [A (ND) | B (ND) | C (ND) | Dh (ND) | Ebuf (2*ND) | degp (N) | degn (N)]
    // A+B contiguous doubles as an N x 2D buffer (neg2 sums, then h_n2).
    // Ebuf is pos2 sums, then h_b2 (in-place GEMM).
    float* A    = ws;
    float* B    = ws + ND;
    float* C    = ws + 2 * ND;   // h_b1
    float* Dh   = ws + 3 * ND;   // h_n1
    float* Ebuf = ws + 4 * ND;
    float* degp = ws + 6 * ND;
    float* degn = degp + N;

    int gridE  = (E + THREADS - 1) / THREADS;
    long st    = (long)E * 32;
    int gridS  = (int)((st + THREADS - 1) / THREADS);
    int gridN2 = (2 * N + THREADS - 1) / THREADS;
    int gridG  = (N + 31) / 32;

    // degrees -> inverse degrees (in place)
    hipMemsetAsync(degp, 0, 2 * (size_t)N * sizeof(float), stream);
    deg_kernel<<<gridE, THREADS, 0, stream>>>(pos_dst, neg_dst, degp, degn, E);
    inv_kernel<<<gridN2, THREADS, 0, stream>>>(degp, 2 * N);

    // layer 1 aggregation: pos1 sums -> A, neg1 sums -> B
    hipMemsetAsync(A, 0, 2 * ND * sizeof(float), stream);
    scatter_add_kernel<<<gridS, THREADS, 0, stream>>>(x, pos_src, pos_dst, A, D, 0, E);
    scatter_add_kernel<<<gridS, THREADS, 0, stream>>>(x, neg_src, neg_dst, B, D, 0, E);

    // layer 1 GEMMs: h_b1 -> C, h_n1 -> Dh
    gemm_tanh<256, 128><<<gridG, THREADS, 0, stream>>>(
        A, degp, D, D, x, nullptr, D, D, nullptr, 0, W_oneB, b_oneB, C, D, N);
    gemm_tanh<256, 128><<<gridG, THREADS, 0, stream>>>(
        B, degn, D, D, x, nullptr, D, D, nullptr, 0, W_oneH, b_oneH, Dh, D, N);

    // layer 2 aggregation: pos2 sums -> Ebuf (N x 2D), neg2 sums -> A..B (N x 2D)
    hipMemsetAsync(A, 0, 2 * ND * sizeof(float), stream);
    hipMemsetAsync(Ebuf, 0, 2 * ND * sizeof(float), stream);
    scatter_add_kernel<<<gridS, THREADS, 0, stream>>>(C,  pos_src, pos_dst, Ebuf, 2 * D, 0, E);
    scatter_add_kernel<<<gridS, THREADS, 0, stream>>>(Dh, neg_src, neg_dst, Ebuf, 2 * D, D, E);
    scatter_add_kernel<<<gridS, THREADS, 0, stream>>>(Dh, pos_src, pos_dst, A,    2 * D, 0, E);
    scatter_add_kernel<<<gridS, THREADS, 0, stream>>>(C,  neg_src, neg_dst, A,    2 * D, D, E);

    // layer 2 GEMMs (in place over their aggregation buffers)
    gemm_tanh<384, 256><<<gridG, THREADS, 0, stream>>>(
        Ebuf, degp, 2 * D, D, Ebuf + D, degn, 2 * D, D, C, D,
        W_twoB, b_twoB, Ebuf, 2 * D, N);
    gemm_tanh<384, 256><<<gridG, THREADS, 0, stream>>>(
        A, degp, 2 * D, D, A + D, degn, 2 * D, D, Dh, D,
        W_twoH, b_twoH, A, 2 * D, N);

    // final GEMM: concat(h_b2, h_n2) @ W_four -> out
    gemm_tanh<512, 128><<<gridG, THREADS, 0, stream>>>(
        Ebuf, nullptr, 2 * D, 2 * D, A, nullptr, 2 * D, 2 * D, nullptr, 0,
        W_four, b_four, (float*)d_out, D, N);
}

// Round 2
// 1751.441 us; speedup vs baseline: 5.3210x; 5.3210x over previous
//
#include <hip/hip_runtime.h>
#include <math.h>

#define THREADS 256

// ---------------- CSR build (counting sort by dst) ----------------

__global__ void count_kernel(const int* __restrict__ pdst, const int* __restrict__ ndst,
                             int* pcnt, int* ncnt, int E) {
    int e = blockIdx.x * blockDim.x + threadIdx.x;
    if (e < E) {
        atomicAdd(&pcnt[pdst[e]], 1);
        atomicAdd(&ncnt[ndst[e]], 1);
    }
}

// single-block in-place exclusive scan: rp[0..n) counts -> exclusive prefix, rp[n]=total
__global__ __launch_bounds__(1024) void scan_kernel(int* rp, int n) {
    __shared__ int sums[1024];
    int t = threadIdx.x;
    int ch = (n + 1023) >> 10;
    int beg = t * ch;
    int end = min(beg + ch, n);
    int s = 0;
    for (int i = beg; i < end; i++) s += rp[i];
    sums[t] = s;
    __syncthreads();
    for (int off = 1; off < 1024; off <<= 1) {
        int v = (t >= off) ? sums[t - off] : 0;
        __syncthreads();
        sums[t] += v;
        __syncthreads();
    }
    int run = (t > 0) ? sums[t - 1] : 0;
    for (int i = beg; i < end; i++) {
        int c = rp[i];
        rp[i] = run;
        run += c;
    }
    if (t == 1023) rp[n] = sums[1023];
}

// fill: atomicAdd on rowptr itself; afterwards rp[i] == original rp[i+1]
// (gather uses beg = node ? rp[node-1] : 0, end = rp[node])
__global__ void fill_kernel(const int* __restrict__ psrc, const int* __restrict__ pdst,
                            const int* __restrict__ nsrc, const int* __restrict__ ndst,
                            int* prow, int* nrow, int* pperm, int* nperm, int E) {
    int e = blockIdx.x * blockDim.x + threadIdx.x;
    if (e < E) {
        int p = atomicAdd(&prow[pdst[e]], 1);
        pperm[p] = psrc[e];
        int q = atomicAdd(&nrow[ndst[e]], 1);
        nperm[q] = nsrc[e];
    }
}

// ---------------- gather-mean aggregation ----------------
// 32 lanes per node, each lane owns a float4 chunk of the 128-wide row.

__global__ __launch_bounds__(256) void gather_mean1(
        const int* __restrict__ rowptr, const int* __restrict__ perm,
        const float* __restrict__ feat, float* __restrict__ out, int n) {
    int node = blockIdx.x * 8 + (threadIdx.x >> 5);
    if (node >= n) return;
    int lane = threadIdx.x & 31;
    int beg = node ? rowptr[node - 1] : 0;
    int end = rowptr[node];
    float4 a0 = make_float4(0.f, 0.f, 0.f, 0.f);
    float4 a1 = make_float4(0.f, 0.f, 0.f, 0.f);
    int i = beg;
    for (; i + 2 <= end; i += 2) {
        int s0 = perm[i], s1 = perm[i + 1];
        float4 v0 = *(const float4*)(feat + (long)s0 * 128 + lane * 4);
        float4 v1 = *(const float4*)(feat + (long)s1 * 128 + lane * 4);
        a0.x += v0.x; a0.y += v0.y; a0.z += v0.z; a0.w += v0.w;
        a1.x += v1.x; a1.y += v1.y; a1.z += v1.z; a1.w += v1.w;
    }
    if (i < end) {
        int s0 = perm[i];
        float4 v0 = *(const float4*)(feat + (long)s0 * 128 + lane * 4);
        a0.x += v0.x; a0.y += v0.y; a0.z += v0.z; a0.w += v0.w;
    }
    float inv = 1.0f / (float)max(end - beg, 1);
    float4 r;
    r.x = (a0.x + a1.x) * inv;
    r.y = (a0.y + a1.y) * inv;
    r.z = (a0.z + a1.z) * inv;
    r.w = (a0.w + a1.w) * inv;
    *(float4*)(out + (long)node * 128 + lane * 4) = r;
}

// dual gather: same CSR, two feature matrices -> two outputs (stride 256, col offset)
__global__ __launch_bounds__(256) void gather_mean2(
        const int* __restrict__ rowptr, const int* __restrict__ perm,
        const float* __restrict__ featA, const float* __restrict__ featB,
        float* __restrict__ outA, float* __restrict__ outB, int coff, int n) {
    int node = blockIdx.x * 8 + (threadIdx.x >> 5);
    if (node >= n) return;
    int lane = threadIdx.x & 31;
    int beg = node ? rowptr[node - 1] : 0;
    int end = rowptr[node];
    float4 a0 = make_float4(0.f, 0.f, 0.f, 0.f);
    float4 b0 = make_float4(0.f, 0.f, 0.f, 0.f);
    for (int i = beg; i < end; i++) {
        int s = perm[i];
        float4 va = *(const float4*)(featA + (long)s * 128 + lane * 4);
        float4 vb = *(const float4*)(featB + (long)s * 128 + lane * 4);
        a0.x += va.x; a0.y += va.y; a0.z += va.z; a0.w += va.w;
        b0.x += vb.x; b0.y += vb.y; b0.z += vb.z; b0.w += vb.w;
    }
    float inv = 1.0f / (float)max(end - beg, 1);
    a0.x *= inv; a0.y *= inv; a0.z *= inv; a0.w *= inv;
    b0.x *= inv; b0.y *= inv; b0.z *= inv; b0.w *= inv;
    *(float4*)(outA + (long)node * 256 + coff + lane * 4) = a0;
    *(float4*)(outB + (long)node * 256 + coff + lane * 4) = b0;
}

// ---------------- GEMM + tanh epilogue ----------------
// Row k-range assembled from up to 3 concatenated parts. In-place safe:
// each block stages its own 32 rows x K into LDS before any store.
template<int K, int OUTC>
__global__ __launch_bounds__(256) void gemm_tanh(
    const float* p0, int st0, int w0,
    const float* p1, int st1, int w1,
    const float* p2, int st2,
    const float* __restrict__ W, const float* __restrict__ bias,
    float* out, int ostride, int n)
{
    __shared__ float Alds[32][K];
    int tid = threadIdx.x;
    int rowBase = blockIdx.x * 32;

    for (int idx = tid; idx < 32 * K; idx += 256) {
        int r = idx / K;
        int k = idx - r * K;
        int row = rowBase + r;
        float v = 0.0f;
        if (row < n) {
            if (k < w0) {
                v = p0[(long)row * st0 + k];
            } else if (k < w0 + w1) {
                v = p1[(long)row * st1 + (k - w0)];
            } else {
                v = p2[(long)row * st2 + (k - w0 - w1)];
            }
        }
        Alds[r][k] = v;
    }
    __syncthreads();

    constexpr int RPT = 32 * OUTC / 256;
    constexpr int RSTEP = 256 / OUTC;
    int col = tid % OUTC;
    int r0 = tid / OUTC;

    float acc[RPT];
    float bv = bias[col];
#pragma unroll
    for (int i = 0; i < RPT; i++) acc[i] = bv;

    for (int k = 0; k < K; k += 4) {
        float w0v = W[(long)(k + 0) * OUTC + col];
        float w1v = W[(long)(k + 1) * OUTC + col];
        float w2v = W[(long)(k + 2) * OUTC + col];
        float w3v = W[(long)(k + 3) * OUTC + col];
#pragma unroll
        for (int i = 0; i < RPT; i++) {
            float4 a = *(const float4*)&Alds[r0 + i * RSTEP][k];
            acc[i] = fmaf(a.x, w0v, acc[i]);
            acc[i] = fmaf(a.y, w1v, acc[i]);
            acc[i] = fmaf(a.z, w2v, acc[i]);
            acc[i] = fmaf(a.w, w3v, acc[i]);
        }
    }

#pragma unroll
    for (int i = 0; i < RPT; i++) {
        int row = rowBase + r0 + i * RSTEP;
        if (row < n) out[(long)row * ostride + col] = tanhf(acc[i]);
    }
}

extern "C" void kernel_launch(void* const* d_in, const int* in_sizes, int n_in,
                              void* d_out, int out_size, void* d_ws, size_t ws_size,
                              hipStream_t stream) {
    const float* x       = (const float*)d_in[0];
    const int*   pos_src = (const int*)d_in[1];
    const int*   pos_dst = (const int*)d_in[2];
    const int*   neg_src = (const int*)d_in[3];
    const int*   neg_dst = (const int*)d_in[4];
    const float* W_oneB  = (const float*)d_in[5];
    const float* b_oneB  = (const float*)d_in[6];
    const float* W_oneH  = (const float*)d_in[7];
    const float* b_oneH  = (const float*)d_in[8];
    const float* W_twoB  = (const float*)d_in[9];
    const float* b_twoB  = (const float*)d_in[10];
    const float* W_twoH  = (const float*)d_in[11];
    const float* b_twoH  = (const float*)d_in[12];
    const float* W_four  = (const float*)d_in[13];
    const float* b_four  = (const float*)d_in[14];

    const int D = in_sizes[6];        // 128
    const int N = in_sizes[0] / D;    // 50000
    const int E = in_sizes[1];        // 800000

    float* ws = (float*)d_ws;
    size_t ND = (size_t)N * D;
    // floats: [A (ND) | B (ND) | C (ND) | Dh (ND) | Ebuf (2*ND)]
    //   A,B: layer-1 means; A..B contiguous reused as N x 2D (neg2 -> h_n2).
    //   C = h_b1, Dh = h_n1. Ebuf = pos2 -> h_b2 (in-place).
    float* A    = ws;
    float* C    = ws + 2 * ND;
    float* Dh   = ws + 3 * ND;
    float* Ebuf = ws + 4 * ND;
    float* Bm   = ws + ND;
    // ints after floats: p_row (N+1) | n_row (N+1) | p_perm (E) | n_perm (E)
    int* ip     = (int*)(ws + 6 * ND);
    int* p_row  = ip;
    int* n_row  = ip + (N + 1);
    int* p_perm = ip + 2 * (N + 1);
    int* n_perm = p_perm + E;

    int gridE = (E + THREADS - 1) / THREADS;
    int gridN8 = (N + 7) / 8;
    int gridG = (N + 31) / 32;

    // CSR build
    hipMemsetAsync(ip, 0, 2 * (size_t)(N + 1) * sizeof(int), stream);
    count_kernel<<<gridE, THREADS, 0, stream>>>(pos_dst, neg_dst, p_row, n_row, E);
    scan_kernel<<<1, 1024, 0, stream>>>(p_row, N);
    scan_kernel<<<1, 1024, 0, stream>>>(n_row, N);
    fill_kernel<<<gridE, THREADS, 0, stream>>>(pos_src, pos_dst, neg_src, neg_dst,
                                               p_row, n_row, p_perm, n_perm, E);

    // layer 1: gather means of x
    gather_mean1<<<gridN8, THREADS, 0, stream>>>(p_row, p_perm, x, A, N);
    gather_mean1<<<gridN8, THREADS, 0, stream>>>(n_row, n_perm, x, Bm, N);

    // layer 1 GEMMs: h_b1 -> C, h_n1 -> Dh
    gemm_tanh<256, 128><<<gridG, THREADS, 0, stream>>>(
        A, D, D, x, D, D, nullptr, 0, W_oneB, b_oneB, C, D, N);
    gemm_tanh<256, 128><<<gridG, THREADS, 0, stream>>>(
        Bm, D, D, x, D, D, nullptr, 0, W_oneH, b_oneH, Dh, D, N);

    // layer 2: dual gathers (pos CSR feeds h_b1->pos2[:,0:D], h_n1->neg2[:,0:D];
    //                        neg CSR feeds h_n1->pos2[:,D:2D], h_b1->neg2[:,D:2D])
    gather_mean2<<<gridN8, THREADS, 0, stream>>>(p_row, p_perm, C, Dh, Ebuf, A, 0, N);
    gather_mean2<<<gridN8, THREADS, 0, stream>>>(n_row, n_perm, Dh, C, Ebuf, A, D, N);

    // layer 2 GEMMs (in place over their aggregation buffers)
    gemm_tanh<384, 256><<<gridG, THREADS, 0, stream>>>(
        Ebuf, 2 * D, D, Ebuf + D, 2 * D, D, C, D,
        W_twoB, b_twoB, Ebuf, 2 * D, N);
    gemm_tanh<384, 256><<<gridG, THREADS, 0, stream>>>(
        A, 2 * D, D, A + D, 2 * D, D, Dh, D,
        W_twoH, b_twoH, A, 2 * D, N);

    // final GEMM: concat(h_b2, h_n2) @ W_four -> out
    gemm_tanh<512, 128><<<gridG, THREADS, 0, stream>>>(
        Ebuf, 2 * D, 2 * D, A, 2 * D, 2 * D, nullptr, 0,
        W_four, b_four, (float*)d_out, D, N);
}

// Round 3
// 842.291 us; speedup vs baseline: 11.0644x; 2.0794x over previous
//
#include <hip/hip_runtime.h>
#include <math.h>

#define THREADS 256

typedef __attribute__((ext_vector_type(8))) short short8;
typedef __attribute__((ext_vector_type(4))) float f32x4;

static __device__ __forceinline__ ushort f2bf(float f) {
    uint u = __float_as_uint(f);
    uint r = (u + 0x7FFFu + ((u >> 16) & 1u)) >> 16;   // RNE
    return (ushort)r;
}
static __device__ __forceinline__ float bf2f(ushort h) {
    return __uint_as_float(((uint)h) << 16);
}

// ---------------- CSR build (counting sort by dst) ----------------

__global__ void count_kernel(const int* __restrict__ pdst, const int* __restrict__ ndst,
                             int* pcnt, int* ncnt, int E) {
    int e = blockIdx.x * blockDim.x + threadIdx.x;
    if (e < E) {
        atomicAdd(&pcnt[pdst[e]], 1);
        atomicAdd(&ncnt[ndst[e]], 1);
    }
}

__global__ __launch_bounds__(1024) void scan_kernel(int* rp, int n) {
    __shared__ int sums[1024];
    int t = threadIdx.x;
    int ch = (n + 1023) >> 10;
    int beg = t * ch;
    int end = min(beg + ch, n);
    int s = 0;
    for (int i = beg; i < end; i++) s += rp[i];
    sums[t] = s;
    __syncthreads();
    for (int off = 1; off < 1024; off <<= 1) {
        int v = (t >= off) ? sums[t - off] : 0;
        __syncthreads();
        sums[t] += v;
        __syncthreads();
    }
    int run = (t > 0) ? sums[t - 1] : 0;
    for (int i = beg; i < end; i++) {
        int c = rp[i];
        rp[i] = run;
        run += c;
    }
    if (t == 1023) rp[n] = sums[1023];
}

__global__ void fill_kernel(const int* __restrict__ psrc, const int* __restrict__ pdst,
                            const int* __restrict__ nsrc, const int* __restrict__ ndst,
                            int* prow, int* nrow, int* pperm, int* nperm, int E) {
    int e = blockIdx.x * blockDim.x + threadIdx.x;
    if (e < E) {
        int p = atomicAdd(&prow[pdst[e]], 1);
        pperm[p] = psrc[e];
        int q = atomicAdd(&nrow[ndst[e]], 1);
        nperm[q] = nsrc[e];
    }
}

// ---------------- fp32 -> bf16 conversions ----------------

__global__ void convert_x(const float* __restrict__ x, ushort* __restrict__ xb, long n8) {
    long o = (long)blockIdx.x * blockDim.x + threadIdx.x;
    if (o >= n8) return;
    long base = o * 8;
    float4 f0 = *(const float4*)(x + base);
    float4 f1 = *(const float4*)(x + base + 4);
    uint4 u;
    u.x = (uint)f2bf(f0.x) | ((uint)f2bf(f0.y) << 16);
    u.y = (uint)f2bf(f0.z) | ((uint)f2bf(f0.w) << 16);
    u.z = (uint)f2bf(f1.x) | ((uint)f2bf(f1.y) << 16);
    u.w = (uint)f2bf(f1.z) | ((uint)f2bf(f1.w) << 16);
    *(uint4*)(xb + base) = u;
}

// W [K][C] fp32 -> WT [C][K] bf16
__global__ void transpose_w(const float* __restrict__ W, ushort* __restrict__ WT,
                            int K, int C) {
    int o = blockIdx.x * blockDim.x + threadIdx.x;
    if (o >= K * C) return;
    int c = o / K;
    int k = o - c * K;
    WT[o] = f2bf(W[(long)k * C + c]);
}

// ---------------- gather-mean aggregation (bf16 in/out, fp32 accum) ----------------
// 32 lanes per node; lane owns 4 contiguous bf16 (8 B) of the 128-wide row.

__global__ __launch_bounds__(256) void gather_mean1(
        const int* __restrict__ rowptr, const int* __restrict__ perm,
        const ushort* __restrict__ feat, ushort* __restrict__ out, int n) {
    int node = blockIdx.x * 8 + (threadIdx.x >> 5);
    if (node >= n) return;
    int lane = threadIdx.x & 31;
    int beg = node ? rowptr[node - 1] : 0;
    int end = rowptr[node];
    float a0 = 0.f, a1 = 0.f, a2 = 0.f, a3 = 0.f;
    float b0 = 0.f, b1 = 0.f, b2 = 0.f, b3 = 0.f;
    int i = beg;
    for (; i + 2 <= end; i += 2) {
        int s0 = perm[i], s1 = perm[i + 1];
        uint2 v0 = *(const uint2*)(feat + (long)s0 * 128 + lane * 4);
        uint2 v1 = *(const uint2*)(feat + (long)s1 * 128 + lane * 4);
        a0 += bf2f((ushort)v0.x); a1 += bf2f((ushort)(v0.x >> 16));
        a2 += bf2f((ushort)v0.y); a3 += bf2f((ushort)(v0.y >> 16));
        b0 += bf2f((ushort)v1.x); b1 += bf2f((ushort)(v1.x >> 16));
        b2 += bf2f((ushort)v1.y); b3 += bf2f((ushort)(v1.y >> 16));
    }
    if (i < end) {
        int s0 = perm[i];
        uint2 v0 = *(const uint2*)(feat + (long)s0 * 128 + lane * 4);
        a0 += bf2f((ushort)v0.x); a1 += bf2f((ushort)(v0.x >> 16));
        a2 += bf2f((ushort)v0.y); a3 += bf2f((ushort)(v0.y >> 16));
    }
    float inv = 1.0f / (float)max(end - beg, 1);
    uint2 r;
    r.x = (uint)f2bf((a0 + b0) * inv) | ((uint)f2bf((a1 + b1) * inv) << 16);
    r.y = (uint)f2bf((a2 + b2) * inv) | ((uint)f2bf((a3 + b3) * inv) << 16);
    *(uint2*)(out + (long)node * 128 + lane * 4) = r;
}

__global__ __launch_bounds__(256) void gather_mean2(
        const int* __restrict__ rowptr, const int* __restrict__ perm,
        const ushort* __restrict__ featA, const ushort* __restrict__ featB,
        ushort* __restrict__ outA, ushort* __restrict__ outB, int coff, int n) {
    int node = blockIdx.x * 8 + (threadIdx.x >> 5);
    if (node >= n) return;
    int lane = threadIdx.x & 31;
    int beg = node ? rowptr[node - 1] : 0;
    int end = rowptr[node];
    float a0 = 0.f, a1 = 0.f, a2 = 0.f, a3 = 0.f;
    float b0 = 0.f, b1 = 0.f, b2 = 0.f, b3 = 0.f;
    for (int i = beg; i < end; i++) {
        int s = perm[i];
        uint2 va = *(const uint2*)(featA + (long)s * 128 + lane * 4);
        uint2 vb = *(const uint2*)(featB + (long)s * 128 + lane * 4);
        a0 += bf2f((ushort)va.x); a1 += bf2f((ushort)(va.x >> 16));
        a2 += bf2f((ushort)va.y); a3 += bf2f((ushort)(va.y >> 16));
        b0 += bf2f((ushort)vb.x); b1 += bf2f((ushort)(vb.x >> 16));
        b2 += bf2f((ushort)vb.y); b3 += bf2f((ushort)(vb.y >> 16));
    }
    float inv = 1.0f / (float)max(end - beg, 1);
    uint2 ra, rb;
    ra.x = (uint)f2bf(a0 * inv) | ((uint)f2bf(a1 * inv) << 16);
    ra.y = (uint)f2bf(a2 * inv) | ((uint)f2bf(a3 * inv) << 16);
    rb.x = (uint)f2bf(b0 * inv) | ((uint)f2bf(b1 * inv) << 16);
    rb.y = (uint)f2bf(b2 * inv) | ((uint)f2bf(b3 * inv) << 16);
    *(uint2*)(outA + (long)node * 256 + coff + lane * 4) = ra;
    *(uint2*)(outB + (long)node * 256 + coff + lane * 4) = rb;
}

// ---------------- bf16 MFMA GEMM + tanh ----------------
// C[M][OUTC] = tanh(concat(A0,A1)[M][K] @ W[K][OUTC] + bias)
// A assembled from two bf16 parts: cols [0,W0) from p0 (stride st0),
// cols [W0,K) from p1 (stride st1). WT is [OUTC][K] bf16 (pre-transposed).
// Block: 256 thr = 4 waves in 2x2; block tile 128 rows x 128 cols; BK=64.
// LDS tiles swizzled: 16B chunk index ^= (row & 7)  (kills stride-128B conflicts).
template<int K, int OUTC, int W0, bool OUTF32>
__global__ __launch_bounds__(256) void mfma_gemm_tanh(
    const ushort* __restrict__ p0, int st0,
    const ushort* __restrict__ p1, int st1,
    const ushort* __restrict__ WT, const float* __restrict__ bias,
    void* __restrict__ outv, int ostride, int M)
{
    __shared__ ushort A_lds[128 * 64];
    __shared__ ushort B_lds[128 * 64];

    int tid = threadIdx.x;
    int rowBase = blockIdx.x * 128;
    int colBase = blockIdx.y * 128;
    int w = tid >> 6, lane = tid & 63;
    int wr = (w >> 1) * 64, wc = (w & 1) * 64;
    int l15 = lane & 15;
    int lk = lane >> 4;            // k-group 0..3

    f32x4 acc[4][4] = {};

    for (int k0 = 0; k0 < K; k0 += 64) {
        // ---- stage A tile: rows rowBase..+128, k in [k0,k0+64) ----
        uint4 va[4], vb[4];
#pragma unroll
        for (int i = 0; i < 4; i++) {
            int idx = tid + i * 256;          // 0..1023 = 128 rows x 8 chunks
            int r = idx >> 3, c = idx & 7;
            int grow = rowBase + r;
            int gk = k0 + c * 8;
            uint4 v = make_uint4(0, 0, 0, 0);
            if (grow < M) {
                const ushort* p; long off;
                if (gk < W0) { p = p0; off = (long)grow * st0 + gk; }
                else         { p = p1; off = (long)grow * st1 + (gk - W0); }
                v = *(const uint4*)(p + off);
            }
            va[i] = v;
            // B tile: WT rows (= output cols) colBase..+128, same k range
            int gcol = colBase + r;
            vb[i] = *(const uint4*)(WT + (long)gcol * K + gk);
        }
        __syncthreads();   // previous iteration's LDS reads complete
#pragma unroll
        for (int i = 0; i < 4; i++) {
            int idx = tid + i * 256;
            int r = idx >> 3, c = idx & 7;
            int cs = (c ^ (r & 7)) * 8;
            *(uint4*)&A_lds[r * 64 + cs] = va[i];
            *(uint4*)&B_lds[r * 64 + cs] = vb[i];
        }
        __syncthreads();

        // ---- compute: 2 k-steps of 32 ----
#pragma unroll
        for (int kk = 0; kk < 2; kk++) {
            short8 af[4], bf[4];
#pragma unroll
            for (int m = 0; m < 4; m++) {
                int rA = wr + m * 16 + l15;
                int ch = (kk * 4 + lk) ^ (rA & 7);
                af[m] = *(const short8*)&A_lds[rA * 64 + ch * 8];
            }
#pragma unroll
            for (int n = 0; n < 4; n++) {
                int rB = wc + n * 16 + l15;
                int ch = (kk * 4 + lk) ^ (rB & 7);
                bf[n] = *(const short8*)&B_lds[rB * 64 + ch * 8];
            }
#pragma unroll
            for (int m = 0; m < 4; m++)
#pragma unroll
                for (int n = 0; n < 4; n++)
                    acc[m][n] = __builtin_amdgcn_mfma_f32_16x16x32_bf16(
                        af[m], bf[n], acc[m][n], 0, 0, 0);
        }
        __syncthreads();
    }

    // ---- epilogue: bias + tanh; C/D layout col=lane&15, row=(lane>>4)*4+j ----
#pragma unroll
    for (int n = 0; n < 4; n++) {
        int col = colBase + wc + n * 16 + l15;
        float bv = bias[col];
#pragma unroll
        for (int m = 0; m < 4; m++) {
            int rbase = rowBase + wr + m * 16 + lk * 4;
#pragma unroll
            for (int j = 0; j < 4; j++) {
                int row = rbase + j;
                if (row < M) {
                    float v = tanhf(acc[m][n][j] + bv);
                    if (OUTF32) ((float*)outv)[(long)row * ostride + col] = v;
                    else        ((ushort*)outv)[(long)row * ostride + col] = f2bf(v);
                }
            }
        }
    }
}

extern "C" void kernel_launch(void* const* d_in, const int* in_sizes, int n_in,
                              void* d_out, int out_size, void* d_ws, size_t ws_size,
                              hipStream_t stream) {
    const float* x       = (const float*)d_in[0];
    const int*   pos_src = (const int*)d_in[1];
    const int*   pos_dst = (const int*)d_in[2];
    const int*   neg_src = (const int*)d_in[3];
    const int*   neg_dst = (const int*)d_in[4];
    const float* W_oneB  = (const float*)d_in[5];
    const float* b_oneB  = (const float*)d_in[6];
    const float* W_oneH  = (const float*)d_in[7];
    const float* b_oneH  = (const float*)d_in[8];
    const float* W_twoB  = (const float*)d_in[9];
    const float* b_twoB  = (const float*)d_in[10];
    const float* W_twoH  = (const float*)d_in[11];
    const float* b_twoH  = (const float*)d_in[12];
    const float* W_four  = (const float*)d_in[13];
    const float* b_four  = (const float*)d_in[14];

    const int D = in_sizes[6];        // 128
    const int N = in_sizes[0] / D;    // 50000
    const int E = in_sizes[1];        // 800000

    ushort* wb = (ushort*)d_ws;
    size_t ND = (size_t)N * D;
    // bf16 buffers:
    ushort* xb   = wb;                 // x in bf16
    ushort* mp   = wb + ND;            // pos1 mean  (mp..mn = 2ND, reused as h_b2)
    ushort* mn   = wb + 2 * ND;        // neg1 mean
    ushort* hb1  = wb + 3 * ND;
    ushort* hn1  = wb + 4 * ND;
    ushort* pos2 = wb + 5 * ND;        // N x 2D, reused as h_n2
    ushort* neg2 = wb + 7 * ND;        // N x 2D
    ushort* hb2  = mp;                 // N x 2D
    ushort* hn2  = pos2;               // N x 2D
    ushort* wt1  = wb + 9 * ND;                    // [D ][2D]^T = 2D*D
    ushort* wt2  = wt1 + 2 * D * D;
    ushort* wt3  = wt2 + 2 * D * D;                // [2D][3D]^T = 3D*2D
    ushort* wt4  = wt3 + 6 * D * D;
    ushort* wt5  = wt4 + 6 * D * D;                // [D ][4D]^T = 4D*D
    int* ip      = (int*)(wt5 + 4 * D * D);
    int* p_row   = ip;
    int* n_row   = ip + (N + 1);
    int* p_perm  = ip + 2 * (N + 1);
    int* n_perm  = p_perm + E;

    int gridE  = (E + THREADS - 1) / THREADS;
    int gridN8 = (N + 7) / 8;
    dim3 g128((N + 127) / 128, 1);
    dim3 g256((N + 127) / 128, 2);

    // CSR build
    hipMemsetAsync(ip, 0, 2 * (size_t)(N + 1) * sizeof(int), stream);
    count_kernel<<<gridE, THREADS, 0, stream>>>(pos_dst, neg_dst, p_row, n_row, E);
    scan_kernel<<<1, 1024, 0, stream>>>(p_row, N);
    scan_kernel<<<1, 1024, 0, stream>>>(n_row, N);
    fill_kernel<<<gridE, THREADS, 0, stream>>>(pos_src, pos_dst, neg_src, neg_dst,
                                               p_row, n_row, p_perm, n_perm, E);

    // conversions
    long n8 = (long)ND / 8;
    convert_x<<<(int)((n8 + 255) / 256), 256, 0, stream>>>(x, xb, n8);
    transpose_w<<<(2*D*D + 255) / 256, 256, 0, stream>>>(W_oneB, wt1, 2 * D, D);
    transpose_w<<<(2*D*D + 255) / 256, 256, 0, stream>>>(W_oneH, wt2, 2 * D, D);
    transpose_w<<<(6*D*D + 255) / 256, 256, 0, stream>>>(W_twoB, wt3, 3 * D, 2 * D);
    transpose_w<<<(6*D*D + 255) / 256, 256, 0, stream>>>(W_twoH, wt4, 3 * D, 2 * D);
    transpose_w<<<(4*D*D + 255) / 256, 256, 0, stream>>>(W_four, wt5, 4 * D, D);

    // layer 1
    gather_mean1<<<gridN8, THREADS, 0, stream>>>(p_row, p_perm, xb, mp, N);
    gather_mean1<<<gridN8, THREADS, 0, stream>>>(n_row, n_perm, xb, mn, N);
    mfma_gemm_tanh<256, 128, 128, false><<<g128, THREADS, 0, stream>>>(
        mp, D, xb, D, wt1, b_oneB, hb1, D, N);
    mfma_gemm_tanh<256, 128, 128, false><<<g128, THREADS, 0, stream>>>(
        mn, D, xb, D, wt2, b_oneH, hn1, D, N);

    // layer 2 aggregation
    gather_mean2<<<gridN8, THREADS, 0, stream>>>(p_row, p_perm, hb1, hn1, pos2, neg2, 0, N);
    gather_mean2<<<gridN8, THREADS, 0, stream>>>(n_row, n_perm, hn1, hb1, pos2, neg2, D, N);

    // layer 2 GEMMs (h_b2 -> mp..mn region; h_n2 -> pos2 region, after B-GEMM done)
    mfma_gemm_tanh<384, 256, 256, false><<<g256, THREADS, 0, stream>>>(
        pos2, 2 * D, hb1, D, wt3, b_twoB, hb2, 2 * D, N);
    mfma_gemm_tanh<384, 256, 256, false><<<g256, THREADS, 0, stream>>>(
        neg2, 2 * D, hn1, D, wt4, b_twoH, hn2, 2 * D, N);

    // final GEMM -> fp32 d_out
    mfma_gemm_tanh<512, 128, 256, true><<<g128, THREADS, 0, stream>>>(
        hb2, 2 * D, hn2, 2 * D, wt5, b_four, d_out, D, N);
}

// Round 4
// 649.717 us; speedup vs baseline: 14.3439x; 1.2964x over previous
//
#include <hip/hip_runtime.h>
#include <math.h>

#define THREADS 256

typedef __attribute__((ext_vector_type(8))) short short8;
typedef __attribute__((ext_vector_type(4))) float f32x4;

static __device__ __forceinline__ ushort f2bf(float f) {
    uint u = __float_as_uint(f);
    uint r = (u + 0x7FFFu + ((u >> 16) & 1u)) >> 16;   // RNE
    return (ushort)r;
}
static __device__ __forceinline__ float bf2f(ushort h) {
    return __uint_as_float(((uint)h) << 16);
}
static __device__ __forceinline__ uint pack2(float a, float b) {
    return (uint)f2bf(a) | ((uint)f2bf(b) << 16);
}

// ---------------- CSR build ----------------
// count: histogram + per-edge rank (free from atomic return)
__global__ void count_kernel(const int* __restrict__ pdst, const int* __restrict__ ndst,
                             int* pcnt, int* ncnt,
                             ushort* __restrict__ prank, ushort* __restrict__ nrank, int E) {
    int e = blockIdx.x * blockDim.x + threadIdx.x;
    if (e < E) {
        prank[e] = (ushort)atomicAdd(&pcnt[pdst[e]], 1);
        nrank[e] = (ushort)atomicAdd(&ncnt[ndst[e]], 1);
    }
}

// two independent in-place exclusive scans (block 0 -> a, block 1 -> b); rp[n]=total
__global__ __launch_bounds__(1024) void scan2_kernel(int* a, int* b, int n) {
    int* rp = blockIdx.x ? b : a;
    __shared__ int sums[1024];
    int t = threadIdx.x;
    int ch = (n + 1023) >> 10;
    int beg = t * ch;
    int end = min(beg + ch, n);
    int s = 0;
    for (int i = beg; i < end; i++) s += rp[i];
    sums[t] = s;
    __syncthreads();
    for (int off = 1; off < 1024; off <<= 1) {
        int v = (t >= off) ? sums[t - off] : 0;
        __syncthreads();
        sums[t] += v;
        __syncthreads();
    }
    int run = (t > 0) ? sums[t - 1] : 0;
    for (int i = beg; i < end; i++) {
        int c = rp[i];
        rp[i] = run;
        run += c;
    }
    if (t == 1023) rp[n] = sums[1023];
}

// fill: no atomics — position = rowptr[dst] + rank[e]
__global__ void fill_kernel(const int* __restrict__ psrc, const int* __restrict__ pdst,
                            const int* __restrict__ nsrc, const int* __restrict__ ndst,
                            const int* __restrict__ prow, const int* __restrict__ nrow,
                            const ushort* __restrict__ prank, const ushort* __restrict__ nrank,
                            ushort* __restrict__ pperm, ushort* __restrict__ nperm, int E) {
    int e = blockIdx.x * blockDim.x + threadIdx.x;
    if (e < E) {
        pperm[prow[pdst[e]] + prank[e]] = (ushort)psrc[e];
        nperm[nrow[ndst[e]] + nrank[e]] = (ushort)nsrc[e];
    }
}

// ---------------- conversions ----------------
__global__ void convert_x(const float* __restrict__ x, ushort* __restrict__ xb, long n8) {
    long o = (long)blockIdx.x * blockDim.x + threadIdx.x;
    if (o >= n8) return;
    long base = o * 8;
    float4 f0 = *(const float4*)(x + base);
    float4 f1 = *(const float4*)(x + base + 4);
    uint4 u;
    u.x = pack2(f0.x, f0.y);
    u.y = pack2(f0.z, f0.w);
    u.z = pack2(f1.x, f1.y);
    u.w = pack2(f1.z, f1.w);
    *(uint4*)(xb + base) = u;
}

// all 5 weight transposes in one launch. W [K][C] fp32 -> WT [C][K] bf16
__global__ void transpose_all(const float* W1, ushort* T1, const float* W2, ushort* T2,
                              const float* W3, ushort* T3, const float* W4, ushort* T4,
                              const float* W5, ushort* T5, int D) {
    int o = blockIdx.x * blockDim.x + threadIdx.x;
    int s1 = 2 * D * D, s3 = 6 * D * D, s5 = 4 * D * D;
    const float* W; ushort* T; int K, C;
    int off = o;
    if (off < s1)              { W = W1; T = T1; K = 2 * D; C = D; }
    else if ((off -= s1) < s1) { W = W2; T = T2; K = 2 * D; C = D; }
    else if ((off -= s1) < s3) { W = W3; T = T3; K = 3 * D; C = 2 * D; }
    else if ((off -= s3) < s3) { W = W4; T = T4; K = 3 * D; C = 2 * D; }
    else if ((off -= s3) < s5) { W = W5; T = T5; K = 4 * D; C = D; }
    else return;
    int c = off / K, k = off - c * K;
    T[off] = f2bf(W[(long)k * C + c]);
}

// ---------------- fused gathers (1 wave = 1 node, both signs) ----------------
// layer 1: mpn[node] = [mean_pos(x) (128) | mean_neg(x) (128)]
__global__ __launch_bounds__(256) void gather_l1(
        const int* __restrict__ p_row, const int* __restrict__ n_row,
        const ushort* __restrict__ p_perm, const ushort* __restrict__ n_perm,
        const ushort* __restrict__ xb, ushort* __restrict__ mpn, int n) {
    int node = blockIdx.x * 4 + (threadIdx.x >> 6);
    if (node >= n) return;
    int lane = threadIdx.x & 63;
    const ushort* base = xb + lane * 2;

    float p0 = 0.f, p1 = 0.f, q0 = 0.f, q1 = 0.f;
    int b = p_row[node], e = p_row[node + 1];
    int i = b;
    for (; i + 2 <= e; i += 2) {
        uint v0 = *(const uint*)(base + (long)p_perm[i] * 128);
        uint v1 = *(const uint*)(base + (long)p_perm[i + 1] * 128);
        p0 += bf2f((ushort)v0); p1 += bf2f((ushort)(v0 >> 16));
        p0 += bf2f((ushort)v1); p1 += bf2f((ushort)(v1 >> 16));
    }
    if (i < e) {
        uint v0 = *(const uint*)(base + (long)p_perm[i] * 128);
        p0 += bf2f((ushort)v0); p1 += bf2f((ushort)(v0 >> 16));
    }
    float invp = 1.0f / (float)max(e - b, 1);

    b = n_row[node]; e = n_row[node + 1];
    i = b;
    for (; i + 2 <= e; i += 2) {
        uint v0 = *(const uint*)(base + (long)n_perm[i] * 128);
        uint v1 = *(const uint*)(base + (long)n_perm[i + 1] * 128);
        q0 += bf2f((ushort)v0); q1 += bf2f((ushort)(v0 >> 16));
        q0 += bf2f((ushort)v1); q1 += bf2f((ushort)(v1 >> 16));
    }
    if (i < e) {
        uint v0 = *(const uint*)(base + (long)n_perm[i] * 128);
        q0 += bf2f((ushort)v0); q1 += bf2f((ushort)(v0 >> 16));
    }
    float invn = 1.0f / (float)max(e - b, 1);

    *(uint*)(mpn + (long)node * 256 + lane * 2)       = pack2(p0 * invp, p1 * invp);
    *(uint*)(mpn + (long)node * 256 + 128 + lane * 2) = pack2(q0 * invn, q1 * invn);
}

// layer 2: reads interleaved hbn1[node] = [hb1|hn1] (512B rows),
// writes pos2[node] = [mean_pos(hb1) | mean_neg(hn1)],
//        neg2[node] = [mean_pos(hn1) | mean_neg(hb1)]
__global__ __launch_bounds__(256) void gather_l2(
        const int* __restrict__ p_row, const int* __restrict__ n_row,
        const ushort* __restrict__ p_perm, const ushort* __restrict__ n_perm,
        const ushort* __restrict__ hbn1,
        ushort* __restrict__ pos2, ushort* __restrict__ neg2, int n) {
    int node = blockIdx.x * 4 + (threadIdx.x >> 6);
    if (node >= n) return;
    int lane = threadIdx.x & 63;
    const ushort* base = hbn1 + lane * 4;

    float aP0 = 0.f, aP1 = 0.f, aP2 = 0.f, aP3 = 0.f;
    float aN0 = 0.f, aN1 = 0.f, aN2 = 0.f, aN3 = 0.f;

    int b = p_row[node], e = p_row[node + 1];
    int i = b;
    for (; i + 2 <= e; i += 2) {
        uint2 v0 = *(const uint2*)(base + (long)p_perm[i] * 256);
        uint2 v1 = *(const uint2*)(base + (long)p_perm[i + 1] * 256);
        aP0 += bf2f((ushort)v0.x); aP1 += bf2f((ushort)(v0.x >> 16));
        aP2 += bf2f((ushort)v0.y); aP3 += bf2f((ushort)(v0.y >> 16));
        aP0 += bf2f((ushort)v1.x); aP1 += bf2f((ushort)(v1.x >> 16));
        aP2 += bf2f((ushort)v1.y); aP3 += bf2f((ushort)(v1.y >> 16));
    }
    if (i < e) {
        uint2 v0 = *(const uint2*)(base + (long)p_perm[i] * 256);
        aP0 += bf2f((ushort)v0.x); aP1 += bf2f((ushort)(v0.x >> 16));
        aP2 += bf2f((ushort)v0.y); aP3 += bf2f((ushort)(v0.y >> 16));
    }
    float invp = 1.0f / (float)max(e - b, 1);

    b = n_row[node]; e = n_row[node + 1];
    i = b;
    for (; i + 2 <= e; i += 2) {
        uint2 v0 = *(const uint2*)(base + (long)n_perm[i] * 256);
        uint2 v1 = *(const uint2*)(base + (long)n_perm[i + 1] * 256);
        aN0 += bf2f((ushort)v0.x); aN1 += bf2f((ushort)(v0.x >> 16));
        aN2 += bf2f((ushort)v0.y); aN3 += bf2f((ushort)(v0.y >> 16));
        aN0 += bf2f((ushort)v1.x); aN1 += bf2f((ushort)(v1.x >> 16));
        aN2 += bf2f((ushort)v1.y); aN3 += bf2f((ushort)(v1.y >> 16));
    }
    if (i < e) {
        uint2 v0 = *(const uint2*)(base + (long)n_perm[i] * 256);
        aN0 += bf2f((ushort)v0.x); aN1 += bf2f((ushort)(v0.x >> 16));
        aN2 += bf2f((ushort)v0.y); aN3 += bf2f((ushort)(v0.y >> 16));
    }
    float invn = 1.0f / (float)max(e - b, 1);

    bool lo = lane < 32;
    float sP = lo ? invp : invn;   // value destined to pos2
    float sN = lo ? invn : invp;   // value destined to neg2
    float vP0 = (lo ? aP0 : aN0) * sP, vP1 = (lo ? aP1 : aN1) * sP;
    float vP2 = (lo ? aP2 : aN2) * sP, vP3 = (lo ? aP3 : aN3) * sP;
    float vN0 = (lo ? aN0 : aP0) * sN, vN1 = (lo ? aN1 : aP1) * sN;
    float vN2 = (lo ? aN2 : aP2) * sN, vN3 = (lo ? aN3 : aP3) * sN;

    uint2 wp, wn;
    wp.x = pack2(vP0, vP1); wp.y = pack2(vP2, vP3);
    wn.x = pack2(vN0, vN1); wn.y = pack2(vN2, vN3);
    *(uint2*)(pos2 + (long)node * 256 + lane * 4) = wp;
    *(uint2*)(neg2 + (long)node * 256 + ((lane + 32) & 63) * 4) = wn;
}

// ---------------- bf16 MFMA GEMM + tanh (z-fused pair) ----------------
template<int K, int OUTC, int W0, bool OUTF32>
__global__ __launch_bounds__(256) void mfma_gemm_tanh(
    const ushort* p0a, const ushort* p0b, int st0,
    const ushort* p1a, const ushort* p1b, int st1,
    const ushort* WTa, const ushort* WTb,
    const float* biasa, const float* biasb,
    void* outa, void* outb, int ostride, int M)
{
    const ushort* p0 = blockIdx.z ? p0b : p0a;
    const ushort* p1 = blockIdx.z ? p1b : p1a;
    const ushort* WT = blockIdx.z ? WTb : WTa;
    const float* bias = blockIdx.z ? biasb : biasa;
    void* outv = blockIdx.z ? outb : outa;

    __shared__ ushort A_lds[128 * 64];
    __shared__ ushort B_lds[128 * 64];

    int tid = threadIdx.x;
    int rowBase = blockIdx.x * 128;
    int colBase = blockIdx.y * 128;
    int w = tid >> 6, lane = tid & 63;
    int wr = (w >> 1) * 64, wc = (w & 1) * 64;
    int l15 = lane & 15;
    int lk = lane >> 4;

    f32x4 acc[4][4] = {};

    for (int k0 = 0; k0 < K; k0 += 64) {
        uint4 va[4], vb[4];
#pragma unroll
        for (int i = 0; i < 4; i++) {
            int idx = tid + i * 256;
            int r = idx >> 3, c = idx & 7;
            int grow = rowBase + r;
            int gk = k0 + c * 8;
            uint4 v = make_uint4(0, 0, 0, 0);
            if (grow < M) {
                const ushort* p; long off;
                if (gk < W0) { p = p0; off = (long)grow * st0 + gk; }
                else         { p = p1; off = (long)grow * st1 + (gk - W0); }
                v = *(const uint4*)(p + off);
            }
            va[i] = v;
            int gcol = colBase + r;
            vb[i] = *(const uint4*)(WT + (long)gcol * K + gk);
        }
        __syncthreads();
#pragma unroll
        for (int i = 0; i < 4; i++) {
            int idx = tid + i * 256;
            int r = idx >> 3, c = idx & 7;
            int cs = (c ^ (r & 7)) * 8;
            *(uint4*)&A_lds[r * 64 + cs] = va[i];
            *(uint4*)&B_lds[r * 64 + cs] = vb[i];
        }
        __syncthreads();

#pragma unroll
        for (int kk = 0; kk < 2; kk++) {
            short8 af[4], bfr[4];
#pragma unroll
            for (int m = 0; m < 4; m++) {
                int rA = wr + m * 16 + l15;
                int ch = (kk * 4 + lk) ^ (rA & 7);
                af[m] = *(const short8*)&A_lds[rA * 64 + ch * 8];
            }
#pragma unroll
            for (int nn = 0; nn < 4; nn++) {
                int rB = wc + nn * 16 + l15;
                int ch = (kk * 4 + lk) ^ (rB & 7);
                bfr[nn] = *(const short8*)&B_lds[rB * 64 + ch * 8];
            }
#pragma unroll
            for (int m = 0; m < 4; m++)
#pragma unroll
                for (int nn = 0; nn < 4; nn++)
                    acc[m][nn] = __builtin_amdgcn_mfma_f32_16x16x32_bf16(
                        af[m], bfr[nn], acc[m][nn], 0, 0, 0);
        }
        __syncthreads();
    }

#pragma unroll
    for (int nn = 0; nn < 4; nn++) {
        int col = colBase + wc + nn * 16 + l15;
        float bv = bias[col];
#pragma unroll
        for (int m = 0; m < 4; m++) {
            int rbase = rowBase + wr + m * 16 + lk * 4;
#pragma unroll
            for (int j = 0; j < 4; j++) {
                int row = rbase + j;
                if (row < M) {
                    float v = tanhf(acc[m][nn][j] + bv);
                    if (OUTF32) ((float*)outv)[(long)row * ostride + col] = v;
                    else        ((ushort*)outv)[(long)row * ostride + col] = f2bf(v);
                }
            }
        }
    }
}

extern "C" void kernel_launch(void* const* d_in, const int* in_sizes, int n_in,
                              void* d_out, int out_size, void* d_ws, size_t ws_size,
                              hipStream_t stream) {
    const float* x       = (const float*)d_in[0];
    const int*   pos_src = (const int*)d_in[1];
    const int*   pos_dst = (const int*)d_in[2];
    const int*   neg_src = (const int*)d_in[3];
    const int*   neg_dst = (const int*)d_in[4];
    const float* W_oneB  = (const float*)d_in[5];
    const float* b_oneB  = (const float*)d_in[6];
    const float* W_oneH  = (const float*)d_in[7];
    const float* b_oneH  = (const float*)d_in[8];
    const float* W_twoB  = (const float*)d_in[9];
    const float* b_twoB  = (const float*)d_in[10];
    const float* W_twoH  = (const float*)d_in[11];
    const float* b_twoH  = (const float*)d_in[12];
    const float* W_four  = (const float*)d_in[13];
    const float* b_four  = (const float*)d_in[14];

    const int D = in_sizes[6];        // 128
    const int N = in_sizes[0] / D;    // 50000  (< 65536 -> ushort perm ok)
    const int E = in_sizes[1];        // 800000

    ushort* wb = (ushort*)d_ws;
    size_t ND = (size_t)N * D;
    // bf16 layout (ushort units):
    //  [0, ND)        xb            }          dead after layer-1 GEMM
    //  [ND, 3ND)      mpn  (Nx256)  }  hbn2 (Nx512) overlays [0,4ND)
    //  [3ND, 4ND)     pad           }
    //  [4ND, 6ND)     hbn1 (Nx256 = [hb1|hn1])
    //  [6ND, 8ND)     pos2 (Nx256)
    //  [8ND, 10ND)    neg2 (Nx256)
    ushort* xb   = wb;
    ushort* mpn  = wb + ND;
    ushort* hbn2 = wb;
    ushort* hbn1 = wb + 4 * ND;
    ushort* pos2 = wb + 6 * ND;
    ushort* neg2 = wb + 8 * ND;
    ushort* wt1  = wb + 10 * ND;
    ushort* wt2  = wt1 + 2 * D * D;
    ushort* wt3  = wt2 + 2 * D * D;
    ushort* wt4  = wt3 + 6 * D * D;
    ushort* wt5  = wt4 + 6 * D * D;
    ushort* p_perm = wt5 + 4 * D * D;
    ushort* n_perm = p_perm + E;
    ushort* p_rank = n_perm + E;
    ushort* n_rank = p_rank + E;
    int* ip    = (int*)(n_rank + E);
    int* p_row = ip;
    int* n_row = ip + (N + 1);

    int gridE  = (E + THREADS - 1) / THREADS;
    int gridN4 = (N + 3) / 4;
    int gx = (N + 127) / 128;
    dim3 g1(gx, 1, 2), g2(gx, 2, 2), g3(gx, 1, 1);

    // CSR build (rank captured in count; fill has no atomics)
    hipMemsetAsync(ip, 0, 2 * (size_t)(N + 1) * sizeof(int), stream);
    count_kernel<<<gridE, THREADS, 0, stream>>>(pos_dst, neg_dst, p_row, n_row,
                                                p_rank, n_rank, E);
    scan2_kernel<<<2, 1024, 0, stream>>>(p_row, n_row, N);
    fill_kernel<<<gridE, THREADS, 0, stream>>>(pos_src, pos_dst, neg_src, neg_dst,
                                               p_row, n_row, p_rank, n_rank,
                                               p_perm, n_perm, E);

    // conversions
    long n8 = (long)ND / 8;
    convert_x<<<(int)((n8 + 255) / 256), 256, 0, stream>>>(x, xb, n8);
    transpose_all<<<(20 * D * D + 255) / 256, 256, 0, stream>>>(
        W_oneB, wt1, W_oneH, wt2, W_twoB, wt3, W_twoH, wt4, W_four, wt5, D);

    // layer 1
    gather_l1<<<gridN4, THREADS, 0, stream>>>(p_row, n_row, p_perm, n_perm, xb, mpn, N);
    mfma_gemm_tanh<256, 128, 128, false><<<g1, THREADS, 0, stream>>>(
        mpn, mpn + 128, 256, xb, xb, 128,
        wt1, wt2, b_oneB, b_oneH, hbn1, hbn1 + 128, 256, N);

    // layer 2
    gather_l2<<<gridN4, THREADS, 0, stream>>>(p_row, n_row, p_perm, n_perm,
                                              hbn1, pos2, neg2, N);
    mfma_gemm_tanh<384, 256, 256, false><<<g2, THREADS, 0, stream>>>(
        pos2, neg2, 256, hbn1, hbn1 + 128, 256,
        wt3, wt4, b_twoB, b_twoH, hbn2, hbn2 + 256, 512, N);

    // final
    mfma_gemm_tanh<512, 128, 512, true><<<g3, THREADS, 0, stream>>>(
        hbn2, hbn2, 512, hbn2, hbn2, 512,
        wt5, wt5, b_four, b_four, d_out, d_out, 128, N);
}

// Round 5
// 588.660 us; speedup vs baseline: 15.8316x; 1.1037x over previous
//
#include <hip/hip_runtime.h>
#include <math.h>

#define THREADS 256

typedef __attribute__((ext_vector_type(8))) short short8;
typedef __attribute__((ext_vector_type(4))) float f32x4;

static __device__ __forceinline__ ushort f2bf(float f) {
    uint u = __float_as_uint(f);
    uint r = (u + 0x7FFFu + ((u >> 16) & 1u)) >> 16;   // RNE
    return (ushort)r;
}
static __device__ __forceinline__ float bf2f(ushort h) {
    return __uint_as_float(((uint)h) << 16);
}
static __device__ __forceinline__ uint pack2(float a, float b) {
    return (uint)f2bf(a) | ((uint)f2bf(b) << 16);
}
// async global->LDS, 16B per lane; LDS dest = wave-uniform base + lane*16
static __device__ __forceinline__ void gload16(const ushort* g, ushort* l) {
    __builtin_amdgcn_global_load_lds(
        (const __attribute__((address_space(1))) void*)g,
        (__attribute__((address_space(3))) void*)l, 16, 0, 0);
}

// ---------------- CSR build ----------------
__global__ void count_kernel(const int* __restrict__ pdst, const int* __restrict__ ndst,
                             int* pcnt, int* ncnt,
                             ushort* __restrict__ prank, ushort* __restrict__ nrank, int E) {
    int e = blockIdx.x * blockDim.x + threadIdx.x;
    if (e < E) {
        prank[e] = (ushort)atomicAdd(&pcnt[pdst[e]], 1);
        nrank[e] = (ushort)atomicAdd(&ncnt[ndst[e]], 1);
    }
}

__global__ __launch_bounds__(1024) void scan2_kernel(int* a, int* b, int n) {
    int* rp = blockIdx.x ? b : a;
    __shared__ int sums[1024];
    int t = threadIdx.x;
    int ch = (n + 1023) >> 10;
    int beg = t * ch;
    int end = min(beg + ch, n);
    int s = 0;
    for (int i = beg; i < end; i++) s += rp[i];
    sums[t] = s;
    __syncthreads();
    for (int off = 1; off < 1024; off <<= 1) {
        int v = (t >= off) ? sums[t - off] : 0;
        __syncthreads();
        sums[t] += v;
        __syncthreads();
    }
    int run = (t > 0) ? sums[t - 1] : 0;
    for (int i = beg; i < end; i++) {
        int c = rp[i];
        rp[i] = run;
        run += c;
    }
    if (t == 1023) rp[n] = sums[1023];
}

__global__ void fill_kernel(const int* __restrict__ psrc, const int* __restrict__ pdst,
                            const int* __restrict__ nsrc, const int* __restrict__ ndst,
                            const int* __restrict__ prow, const int* __restrict__ nrow,
                            const ushort* __restrict__ prank, const ushort* __restrict__ nrank,
                            ushort* __restrict__ pperm, ushort* __restrict__ nperm, int E) {
    int e = blockIdx.x * blockDim.x + threadIdx.x;
    if (e < E) {
        pperm[prow[pdst[e]] + prank[e]] = (ushort)psrc[e];
        nperm[nrow[ndst[e]] + nrank[e]] = (ushort)nsrc[e];
    }
}

// ---------------- conversions ----------------
__global__ void convert_x(const float* __restrict__ x, ushort* __restrict__ xb, long n8) {
    long o = (long)blockIdx.x * blockDim.x + threadIdx.x;
    if (o >= n8) return;
    long base = o * 8;
    float4 f0 = *(const float4*)(x + base);
    float4 f1 = *(const float4*)(x + base + 4);
    uint4 u;
    u.x = pack2(f0.x, f0.y);
    u.y = pack2(f0.z, f0.w);
    u.z = pack2(f1.x, f1.y);
    u.w = pack2(f1.z, f1.w);
    *(uint4*)(xb + base) = u;
}

__global__ void transpose_all(const float* W1, ushort* T1, const float* W2, ushort* T2,
                              const float* W3, ushort* T3, const float* W4, ushort* T4,
                              const float* W5, ushort* T5, int D) {
    int o = blockIdx.x * blockDim.x + threadIdx.x;
    int s1 = 2 * D * D, s3 = 6 * D * D, s5 = 4 * D * D;
    const float* W; ushort* T; int K, C;
    int off = o;
    if (off < s1)              { W = W1; T = T1; K = 2 * D; C = D; }
    else if ((off -= s1) < s1) { W = W2; T = T2; K = 2 * D; C = D; }
    else if ((off -= s1) < s3) { W = W3; T = T3; K = 3 * D; C = 2 * D; }
    else if ((off -= s3) < s3) { W = W4; T = T4; K = 3 * D; C = 2 * D; }
    else if ((off -= s3) < s5) { W = W5; T = T5; K = 4 * D; C = D; }
    else return;
    int c = off / K, k = off - c * K;
    T[off] = f2bf(W[(long)k * C + c]);
}

// ---------------- fused gathers (1 wave = 1 node, both signs) ----------------
__global__ __launch_bounds__(256) void gather_l1(
        const int* __restrict__ p_row, const int* __restrict__ n_row,
        const ushort* __restrict__ p_perm, const ushort* __restrict__ n_perm,
        const ushort* __restrict__ xb, ushort* __restrict__ mpn, int n) {
    int node = blockIdx.x * 4 + (threadIdx.x >> 6);
    if (node >= n) return;
    int lane = threadIdx.x & 63;
    const ushort* base = xb + lane * 2;

    float p0 = 0.f, p1 = 0.f, q0 = 0.f, q1 = 0.f;
    int b = p_row[node], e = p_row[node + 1];
    int i = b;
    for (; i + 2 <= e; i += 2) {
        uint v0 = *(const uint*)(base + (long)p_perm[i] * 128);
        uint v1 = *(const uint*)(base + (long)p_perm[i + 1] * 128);
        p0 += bf2f((ushort)v0); p1 += bf2f((ushort)(v0 >> 16));
        p0 += bf2f((ushort)v1); p1 += bf2f((ushort)(v1 >> 16));
    }
    if (i < e) {
        uint v0 = *(const uint*)(base + (long)p_perm[i] * 128);
        p0 += bf2f((ushort)v0); p1 += bf2f((ushort)(v0 >> 16));
    }
    float invp = 1.0f / (float)max(e - b, 1);

    b = n_row[node]; e = n_row[node + 1];
    i = b;
    for (; i + 2 <= e; i += 2) {
        uint v0 = *(const uint*)(base + (long)n_perm[i] * 128);
        uint v1 = *(const uint*)(base + (long)n_perm[i + 1] * 128);
        q0 += bf2f((ushort)v0); q1 += bf2f((ushort)(v0 >> 16));
        q0 += bf2f((ushort)v1); q1 += bf2f((ushort)(v1 >> 16));
    }
    if (i < e) {
        uint v0 = *(const uint*)(base + (long)n_perm[i] * 128);
        q0 += bf2f((ushort)v0); q1 += bf2f((ushort)(v0 >> 16));
    }
    float invn = 1.0f / (float)max(e - b, 1);

    *(uint*)(mpn + (long)node * 256 + lane * 2)       = pack2(p0 * invp, p1 * invp);
    *(uint*)(mpn + (long)node * 256 + 128 + lane * 2) = pack2(q0 * invn, q1 * invn);
}

__global__ __launch_bounds__(256) void gather_l2(
        const int* __restrict__ p_row, const int* __restrict__ n_row,
        const ushort* __restrict__ p_perm, const ushort* __restrict__ n_perm,
        const ushort* __restrict__ hbn1,
        ushort* __restrict__ pos2, ushort* __restrict__ neg2, int n) {
    int node = blockIdx.x * 4 + (threadIdx.x >> 6);
    if (node >= n) return;
    int lane = threadIdx.x & 63;
    const ushort* base = hbn1 + lane * 4;

    float aP0 = 0.f, aP1 = 0.f, aP2 = 0.f, aP3 = 0.f;
    float aN0 = 0.f, aN1 = 0.f, aN2 = 0.f, aN3 = 0.f;

    int b = p_row[node], e = p_row[node + 1];
    int i = b;
    for (; i + 2 <= e; i += 2) {
        uint2 v0 = *(const uint2*)(base + (long)p_perm[i] * 256);
        uint2 v1 = *(const uint2*)(base + (long)p_perm[i + 1] * 256);
        aP0 += bf2f((ushort)v0.x); aP1 += bf2f((ushort)(v0.x >> 16));
        aP2 += bf2f((ushort)v0.y); aP3 += bf2f((ushort)(v0.y >> 16));
        aP0 += bf2f((ushort)v1.x); aP1 += bf2f((ushort)(v1.x >> 16));
        aP2 += bf2f((ushort)v1.y); aP3 += bf2f((ushort)(v1.y >> 16));
    }
    if (i < e) {
        uint2 v0 = *(const uint2*)(base + (long)p_perm[i] * 256);
        aP0 += bf2f((ushort)v0.x); aP1 += bf2f((ushort)(v0.x >> 16));
        aP2 += bf2f((ushort)v0.y); aP3 += bf2f((ushort)(v0.y >> 16));
    }
    float invp = 1.0f / (float)max(e - b, 1);

    b = n_row[node]; e = n_row[node + 1];
    i = b;
    for (; i + 2 <= e; i += 2) {
        uint2 v0 = *(const uint2*)(base + (long)n_perm[i] * 256);
        uint2 v1 = *(const uint2*)(base + (long)n_perm[i + 1] * 256);
        aN0 += bf2f((ushort)v0.x); aN1 += bf2f((ushort)(v0.x >> 16));
        aN2 += bf2f((ushort)v0.y); aN3 += bf2f((ushort)(v0.y >> 16));
        aN0 += bf2f((ushort)v1.x); aN1 += bf2f((ushort)(v1.x >> 16));
        aN2 += bf2f((ushort)v1.y); aN3 += bf2f((ushort)(v1.y >> 16));
    }
    if (i < e) {
        uint2 v0 = *(const uint2*)(base + (long)n_perm[i] * 256);
        aN0 += bf2f((ushort)v0.x); aN1 += bf2f((ushort)(v0.x >> 16));
        aN2 += bf2f((ushort)v0.y); aN3 += bf2f((ushort)(v0.y >> 16));
    }
    float invn = 1.0f / (float)max(e - b, 1);

    bool lo = lane < 32;
    float sP = lo ? invp : invn;
    float sN = lo ? invn : invp;
    float vP0 = (lo ? aP0 : aN0) * sP, vP1 = (lo ? aP1 : aN1) * sP;
    float vP2 = (lo ? aP2 : aN2) * sP, vP3 = (lo ? aP3 : aN3) * sP;
    float vN0 = (lo ? aN0 : aP0) * sN, vN1 = (lo ? aN1 : aP1) * sN;
    float vN2 = (lo ? aN2 : aP2) * sN, vN3 = (lo ? aN3 : aP3) * sN;

    uint2 wp, wn;
    wp.x = pack2(vP0, vP1); wp.y = pack2(vP2, vP3);
    wn.x = pack2(vN0, vN1); wn.y = pack2(vN2, vN3);
    *(uint2*)(pos2 + (long)node * 256 + lane * 4) = wp;
    *(uint2*)(neg2 + (long)node * 256 + ((lane + 32) & 63) * 4) = wn;
}

// ---------------- bf16 MFMA GEMM + tanh (z-fused pair) ----------------
// Staging: global_load_lds width-16, linear LDS dest, XOR-swizzle applied to the
// per-lane GLOBAL source chunk (c = (lane&7)^(lane>>3)); ds_read side unchanged.
// Epilogue: tanh results restaged in padded LDS, stored as coalesced uint4/float4.
template<int K, int OUTC, int W0, bool OUTF32>
__global__ __launch_bounds__(256) void mfma_gemm_tanh(
    const ushort* p0a, const ushort* p0b, int st0,
    const ushort* p1a, const ushort* p1b, int st1,
    const ushort* WTa, const ushort* WTb,
    const float* biasa, const float* biasb,
    void* outa, void* outb, int ostride, int M)
{
    const ushort* p0 = blockIdx.z ? p0b : p0a;
    const ushort* p1 = blockIdx.z ? p1b : p1a;
    const ushort* WT = blockIdx.z ? WTb : WTa;
    const float* bias = blockIdx.z ? biasb : biasa;
    void* outv = blockIdx.z ? outb : outa;

    // staging: A tile [128 rows][8 chunks of 16B] = 8192 ushort, B same.
    // epilogue: bf16 tile 128x136 (17408) or fp32 half-tile 64x132 (16896 ush).
    __shared__ __align__(16) ushort S[17408];
    ushort* A_lds = S;
    ushort* B_lds = S + 8192;

    int tid = threadIdx.x;
    int rowBase = blockIdx.x * 128;
    int colBase = blockIdx.y * 128;
    int w = tid >> 6, lane = tid & 63;
    int wr = (w >> 1) * 64, wc = (w & 1) * 64;
    int l15 = lane & 15;
    int lk = lane >> 4;

    // per-lane staging geometry (unit u covers rows 8u..8u+7, 1KB per wave-call)
    int sr = lane >> 3;                    // row within unit
    int sc = (lane & 7) ^ sr;              // source chunk for linear slot lane&7

    f32x4 acc[4][4] = {};

    for (int k0 = 0; k0 < K; k0 += 64) {
        const ushort* pA; int stA, kloc;
        if (k0 < W0) { pA = p0; stA = st0; kloc = k0; }
        else         { pA = p1; stA = st1; kloc = k0 - W0; }

        __syncthreads();   // prev iteration's ds_reads done before overwrite
#pragma unroll
        for (int i = 0; i < 4; i++) {
            int u = w * 4 + i;
            int r = u * 8 + sr;
            int grow = rowBase + r;
            if (grow >= M) grow = M - 1;
            gload16(pA + (long)grow * stA + kloc + sc * 8, A_lds + u * 512);
            gload16(WT + (long)(colBase + r) * K + k0 + sc * 8, B_lds + u * 512);
        }
        __syncthreads();   // vmcnt(0) drain + barrier: tiles visible

#pragma unroll
        for (int kk = 0; kk < 2; kk++) {
            short8 af[4], bfr[4];
#pragma unroll
            for (int m = 0; m < 4; m++) {
                int rA = wr + m * 16 + l15;
                int ch = (kk * 4 + lk) ^ (rA & 7);
                af[m] = *(const short8*)&A_lds[rA * 64 + ch * 8];
            }
#pragma unroll
            for (int nn = 0; nn < 4; nn++) {
                int rB = wc + nn * 16 + l15;
                int ch = (kk * 4 + lk) ^ (rB & 7);
                bfr[nn] = *(const short8*)&B_lds[rB * 64 + ch * 8];
            }
#pragma unroll
            for (int m = 0; m < 4; m++)
#pragma unroll
                for (int nn = 0; nn < 4; nn++)
                    acc[m][nn] = __builtin_amdgcn_mfma_f32_16x16x32_bf16(
                        af[m], bfr[nn], acc[m][nn], 0, 0, 0);
        }
    }

    if (!OUTF32) {
        // ---- bf16 epilogue: LDS restage (stride 136) + coalesced uint4 stores ----
        __syncthreads();
#pragma unroll
        for (int nn = 0; nn < 4; nn++) {
            int cl = wc + nn * 16 + l15;
            float bv = bias[colBase + cl];
#pragma unroll
            for (int m = 0; m < 4; m++) {
                int rl = wr + m * 16 + lk * 4;
#pragma unroll
                for (int j = 0; j < 4; j++)
                    S[(rl + j) * 136 + cl] = f2bf(tanhf(acc[m][nn][j] + bv));
            }
        }
        __syncthreads();
#pragma unroll
        for (int it = 0; it < 8; it++) {
            int idx = tid + it * 256;          // 128 rows x 16 chunks
            int r2 = idx >> 4, c2 = idx & 15;
            int grow = rowBase + r2;
            if (grow < M) {
                uint4 v = *(const uint4*)&S[r2 * 136 + c2 * 8];
                *(uint4*)((ushort*)outv + (long)grow * ostride + colBase + c2 * 8) = v;
            }
        }
    } else {
        // ---- fp32 epilogue: two half-tiles of 64 rows (stride 132 floats) ----
        float* Sf = (float*)S;
#pragma unroll
        for (int p = 0; p < 2; p++) {
            __syncthreads();
            if ((wr >> 6) == p) {
#pragma unroll
                for (int nn = 0; nn < 4; nn++) {
                    int cl = wc + nn * 16 + l15;
                    float bv = bias[colBase + cl];
#pragma unroll
                    for (int m = 0; m < 4; m++) {
                        int rl = m * 16 + lk * 4;
#pragma unroll
                        for (int j = 0; j < 4; j++)
                            Sf[(rl + j) * 132 + cl] = tanhf(acc[m][nn][j] + bv);
                    }
                }
            }
            __syncthreads();
#pragma unroll
            for (int it = 0; it < 8; it++) {
                int idx = tid + it * 256;       // 64 rows x 32 float4-chunks
                int r2 = idx >> 5, c2 = idx & 31;
                int grow = rowBase + p * 64 + r2;
                if (grow < M) {
                    float4 v = *(const float4*)&Sf[r2 * 132 + c2 * 4];
                    *(float4*)((float*)outv + (long)grow * ostride + colBase + c2 * 4) = v;
                }
            }
        }
    }
}

extern "C" void kernel_launch(void* const* d_in, const int* in_sizes, int n_in,
                              void* d_out, int out_size, void* d_ws, size_t ws_size,
                              hipStream_t stream) {
    const float* x       = (const float*)d_in[0];
    const int*   pos_src = (const int*)d_in[1];
    const int*   pos_dst = (const int*)d_in[2];
    const int*   neg_src = (const int*)d_in[3];
    const int*   neg_dst = (const int*)d_in[4];
    const float* W_oneB  = (const float*)d_in[5];
    const float* b_oneB  = (const float*)d_in[6];
    const float* W_oneH  = (const float*)d_in[7];
    const float* b_oneH  = (const float*)d_in[8];
    const float* W_twoB  = (const float*)d_in[9];
    const float* b_twoB  = (const float*)d_in[10];
    const float* W_twoH  = (const float*)d_in[11];
    const float* b_twoH  = (const float*)d_in[12];
    const float* W_four  = (const float*)d_in[13];
    const float* b_four  = (const float*)d_in[14];

    const int D = in_sizes[6];        // 128
    const int N = in_sizes[0] / D;    // 50000  (< 65536 -> ushort perm ok)
    const int E = in_sizes[1];        // 800000

    ushort* wb = (ushort*)d_ws;
    size_t ND = (size_t)N * D;
    ushort* xb   = wb;
    ushort* mpn  = wb + ND;
    ushort* hbn2 = wb;
    ushort* hbn1 = wb + 4 * ND;
    ushort* pos2 = wb + 6 * ND;
    ushort* neg2 = wb + 8 * ND;
    ushort* wt1  = wb + 10 * ND;
    ushort* wt2  = wt1 + 2 * D * D;
    ushort* wt3  = wt2 + 2 * D * D;
    ushort* wt4  = wt3 + 6 * D * D;
    ushort* wt5  = wt4 + 6 * D * D;
    ushort* p_perm = wt5 + 4 * D * D;
    ushort* n_perm = p_perm + E;
    ushort* p_rank = n_perm + E;
    ushort* n_rank = p_rank + E;
    int* ip    = (int*)(n_rank + E);
    int* p_row = ip;
    int* n_row = ip + (N + 1);

    int gridE  = (E + THREADS - 1) / THREADS;
    int gridN4 = (N + 3) / 4;
    int gx = (N + 127) / 128;
    dim3 g1(gx, 1, 2), g2(gx, 2, 2), g3(gx, 1, 1);

    // CSR build
    hipMemsetAsync(ip, 0, 2 * (size_t)(N + 1) * sizeof(int), stream);
    count_kernel<<<gridE, THREADS, 0, stream>>>(pos_dst, neg_dst, p_row, n_row,
                                                p_rank, n_rank, E);
    scan2_kernel<<<2, 1024, 0, stream>>>(p_row, n_row, N);
    fill_kernel<<<gridE, THREADS, 0, stream>>>(pos_src, pos_dst, neg_src, neg_dst,
                                               p_row, n_row, p_rank, n_rank,
                                               p_perm, n_perm, E);

    // conversions
    long n8 = (long)ND / 8;
    convert_x<<<(int)((n8 + 255) / 256), 256, 0, stream>>>(x, xb, n8);
    transpose_all<<<(20 * D * D + 255) / 256, 256, 0, stream>>>(
        W_oneB, wt1, W_oneH, wt2, W_twoB, wt3, W_twoH, wt4, W_four, wt5, D);

    // layer 1
    gather_l1<<<gridN4, THREADS, 0, stream>>>(p_row, n_row, p_perm, n_perm, xb, mpn, N);
    mfma_gemm_tanh<256, 128, 128, false><<<g1, THREADS, 0, stream>>>(
        mpn, mpn + 128, 256, xb, xb, 128,
        wt1, wt2, b_oneB, b_oneH, hbn1, hbn1 + 128, 256, N);

    // layer 2
    gather_l2<<<gridN4, THREADS, 0, stream>>>(p_row, n_row, p_perm, n_perm,
                                              hbn1, pos2, neg2, N);
    mfma_gemm_tanh<384, 256, 256, false><<<g2, THREADS, 0, stream>>>(
        pos2, neg2, 256, hbn1, hbn1 + 128, 256,
        wt3, wt4, b_twoB, b_twoH, hbn2, hbn2 + 256, 512, N);

    // final
    mfma_gemm_tanh<512, 128, 512, true><<<g3, THREADS, 0, stream>>>(
        hbn2, hbn2, 512, hbn2, hbn2, 512,
        wt5, wt5, b_four, b_four, d_out, d_out, 128, N);
}